// Round 15
// baseline (709.096 us; speedup 1.0000x reference)
//
#include <hip/hip_runtime.h>

#define EPS_BN 1e-5f

constexpr int NN   = 20000;       // nodes
constexpr int NE   = 320000;      // edges
constexpr int NTOT = NE + NN;     // edges + self loops
constexpr int NG   = 512;        // graphs
constexpr int MPAD = 20480;       // 160 * 128 rows
constexpr int NBLK = 79;          // ceil(NN/256)

typedef _Float16 half8  __attribute__((ext_vector_type(8)));
typedef _Float16 half2v __attribute__((ext_vector_type(2)));
typedef float floatx4   __attribute__((ext_vector_type(4)));

// ------------------------------------------------------------------
// Graph preprocessing
// ------------------------------------------------------------------
__global__ void k_deg(const int* __restrict__ col, int* __restrict__ deg,
                      const int* __restrict__ batch, int* __restrict__ gcnt) {
  int e = blockIdx.x * blockDim.x + threadIdx.x;
  if (e >= NTOT) return;
  int c = (e < NE) ? col[e] : (e - NE);
  atomicAdd(&deg[c], 1);
  if (e < NN) atomicAdd(&gcnt[batch[e]], 1);
}

__global__ __launch_bounds__(256) void k_pre1(const int* __restrict__ deg,
                                              float* __restrict__ dinvv,
                                              int* __restrict__ psum) {
  __shared__ int ws[4];
  int t = threadIdx.x, lane = t & 63, wv = t >> 6;
  int idx = blockIdx.x * 256 + t;
  int d = (idx < NN) ? deg[idx] : 0;
  if (idx < NN) dinvv[idx] = rsqrtf((float)d);
  int s = d;
  for (int o = 1; o < 64; o <<= 1) { int u = __shfl_up(s, o, 64); if (lane >= o) s += u; }
  if (lane == 63) ws[wv] = s;
  __syncthreads();
  if (t == 0) psum[blockIdx.x] = ws[0] + ws[1] + ws[2] + ws[3];
}

__global__ __launch_bounds__(256) void k_pre2(const int* __restrict__ psum,
                                              int* __restrict__ pbase,
                                              const int* __restrict__ gcnt,
                                              int* __restrict__ goff) {
  __shared__ int ws[8];
  int t = threadIdx.x, lane = t & 63, wv = t >> 6;
  int v = (t < NBLK) ? psum[t] : 0;
  int inc = v;
  for (int o = 1; o < 64; o <<= 1) { int u = __shfl_up(inc, o, 64); if (lane >= o) inc += u; }
  if (lane == 63) ws[wv] = inc;
  __syncthreads();
  int base = 0;
  for (int w = 0; w < wv; ++w) base += ws[w];
  int excl = base + inc - v;
  if (t < NBLK) pbase[t] = excl;
  if (t == NBLK - 1) pbase[NBLK] = excl + v;
  __syncthreads();
  int a0 = gcnt[2 * t], a1 = gcnt[2 * t + 1];
  int p = a0 + a1;
  int incp = p;
  for (int o = 1; o < 64; o <<= 1) { int u = __shfl_up(incp, o, 64); if (lane >= o) incp += u; }
  if (lane == 63) ws[4 + wv] = incp;
  __syncthreads();
  int gb = 0;
  for (int w = 0; w < wv; ++w) gb += ws[4 + w];
  int exclp = gb + incp - p;
  goff[2 * t]     = exclp;
  goff[2 * t + 1] = exclp + a0;
  if (t == 255) goff[NG] = exclp + p;
}

__global__ __launch_bounds__(256) void k_pre3(const int* __restrict__ deg,
                                              const int* __restrict__ pbase,
                                              int* __restrict__ indptr,
                                              int* __restrict__ cursor) {
  __shared__ int ws[4];
  int t = threadIdx.x, lane = t & 63, wv = t >> 6;
  int idx = blockIdx.x * 256 + t;
  int d = (idx < NN) ? deg[idx] : 0;
  int inc = d;
  for (int o = 1; o < 64; o <<= 1) { int u = __shfl_up(inc, o, 64); if (lane >= o) inc += u; }
  if (lane == 63) ws[wv] = inc;
  __syncthreads();
  int base = pbase[blockIdx.x];
  for (int w = 0; w < wv; ++w) base += ws[w];
  int excl = base + inc - d;
  if (idx < NN) { indptr[idx] = excl; cursor[idx] = excl; }
  if (idx == NN - 1) indptr[NN] = excl + d;
}

__global__ void k_fill(const int* __restrict__ row, const int* __restrict__ col,
                       const float* __restrict__ dinv, int* __restrict__ cursor,
                       int2* __restrict__ csw, float* __restrict__ rsum) {
  int e = blockIdx.x * blockDim.x + threadIdx.x;
  if (e >= NTOT) return;
  int r, c;
  if (e < NE) { r = row[e]; c = col[e]; } else { r = c = e - NE; }
  float wv = dinv[r] * dinv[c];
  int pos = atomicAdd(&cursor[c], 1);
  int2 m; m.x = r; m.y = __builtin_bit_cast(int, wv);
  csw[pos] = m;
  atomicAdd(&rsum[c], wv);
}

// ------------------------------------------------------------------
// MFMA fragment layout: element (n, k) of an [Nrows, K] operand lives at
// ((n>>4)*(K>>5) + (k>>5))*512 + ((k>>3)&3)*128 + (n&15)*8 + (k&7)
// ------------------------------------------------------------------
__device__ __forceinline__ size_t fragoff(int n, int k, int kb) {
  return ((size_t)(n >> 4) * kb + (k >> 5)) * 512 + ((k >> 3) & 3) * 128 + (n & 15) * 8;
}

__global__ void k_wconv3(const float* __restrict__ W0, const float* __restrict__ W3,
                         const float* __restrict__ W4,
                         _Float16* __restrict__ T0, _Float16* __restrict__ T3,
                         _Float16* __restrict__ T4) {
  int c = blockIdx.x * blockDim.x + threadIdx.x;   // 16B chunk index
  _Float16 ov[8];
  if (c < 4096) {                                  // W1: N=1024, Kp=32 (K=29)
    int n = c >> 2, k = (c & 3) * 8;
    #pragma unroll
    for (int i = 0; i < 8; ++i)
      ov[i] = (_Float16)((k + i < 29) ? W0[(size_t)(k + i) * 1024 + n] : 0.f);
    *(uint4*)&T0[fragoff(n, k, 1)] = *(const uint4*)ov;
  } else if (c < 4096 + 16384) {                   // W4: N=512, K=256
    int c2 = c - 4096;
    int n = c2 >> 5, k = (c2 & 31) * 8;
    #pragma unroll
    for (int i = 0; i < 8; ++i)
      ov[i] = (_Float16)W3[(size_t)(k + i) * 512 + n];
    *(uint4*)&T3[fragoff(n, k, 8)] = *(const uint4*)ov;
  } else if (c < 4096 + 16384 + 65536) {           // W5: N=1024, K=512
    int c3 = c - 20480;
    int n = c3 >> 6, k = (c3 & 63) * 8;
    #pragma unroll
    for (int i = 0; i < 8; ++i)
      ov[i] = (_Float16)W4[(size_t)(k + i) * 1024 + n];
    *(uint4*)&T4[fragoff(n, k, 16)] = *(const uint4*)ov;
  }
}

// W' = diag(sc) W -> fragment layout fp16; c[n] = sum_k sh_k W[k,n]
__global__ __launch_bounds__(256) void k_wfold(const float* __restrict__ W, int K, int N,
                                               const float* __restrict__ sums,
                                               const float* __restrict__ gamma,
                                               const float* __restrict__ beta,
                                               _Float16* __restrict__ T,
                                               float* __restrict__ c) {
  __shared__ float red[256];
  int n = blockIdx.x, tid = threadIdx.x;
  int kb = K >> 5;
  const float inv_n = 1.f / NN;
  float csum = 0.f;
  for (int kc = tid; kc < (K >> 3); kc += 256) {
    int k = kc * 8;
    _Float16 ov[8];
    #pragma unroll
    for (int i = 0; i < 8; ++i) {
      int ki = k + i;
      float mean = sums[ki] * inv_n;
      float var  = sums[K + ki] * inv_n - mean * mean;
      float sc   = gamma[ki] * rsqrtf(var + EPS_BN);
      float sh   = beta[ki] - mean * sc;
      float wv   = W[(size_t)ki * N + n];
      ov[i] = (_Float16)(sc * wv);
      csum += sh * wv;
    }
    *(uint4*)&T[fragoff(n, k, kb)] = *(const uint4*)ov;
  }
  red[tid] = csum;
  __syncthreads();
  for (int o = 128; o > 0; o >>= 1) {
    if (tid < o) red[tid] += red[tid + o];
    __syncthreads();
  }
  if (tid == 0) c[n] = red[0];
}

// ------------------------------------------------------------------
// L1 aggregation: fp32 x (F=29) -> fp16 FRAGMENT out (Kp=32, kb=1)
// ------------------------------------------------------------------
#define AGG_CH 128
__global__ __launch_bounds__(128) void k_agg29(
    const float* __restrict__ X,
    const int* __restrict__ indptr, const int2* __restrict__ csw,
    _Float16* __restrict__ Y) {
  __shared__ int   s_src[AGG_CH];
  __shared__ float s_w[AGG_CH];
  __shared__ float red[128];
  int node = blockIdx.x;
  int tid  = threadIdx.x;
  int sub  = tid / 29;
  int feat = tid - sub * 29;
  bool act = tid < 116;
  int beg = indptr[node], end = indptr[node + 1];
  float acc = 0.f;
  for (int e0 = beg; e0 < end; e0 += AGG_CH) {
    int c = min(AGG_CH, end - e0);
    if (tid < c) {
      int2 m = csw[e0 + tid];
      s_src[tid] = m.x;
      s_w[tid]   = __builtin_bit_cast(float, m.y);
    }
    __syncthreads();
    if (act) {
      for (int j = 0; j < c; j += 4) {
        int jj = j + sub;
        if (jj < c) acc += s_w[jj] * X[(size_t)s_src[jj] * 29 + feat];
      }
    }
    __syncthreads();
  }
  red[tid] = acc;
  __syncthreads();
  if (tid < 32) {
    float v = 0.f;
    if (tid < 29) v = red[tid] + red[29 + tid] + red[58 + tid] + red[87 + tid];
    size_t fb = (size_t)(node >> 4) * 512 + (size_t)(tid >> 3) * 128 + (node & 15) * 8 + (tid & 7);
    Y[fb] = (_Float16)v;
  }
}

// ------------------------------------------------------------------
// XCD-pinned feature-chunked gather aggregation.
// chunk = blockIdx & (NCH-1) rides the round-robin block->XCD mapping,
// so each XCD touches only a 64-feature source slice (20000*128B =
// 2.5 MB < 4 MB L2) -> gather reads become L2 hits.
// Block = 16 nodes x one 64-feat chunk; 4 waves x 4 nodes; lane = feat.
// MODE 0: v = relu(acc + s*p0[f] + p1[f]); MODE 1: BN fold from sums.
// ROWOUT=1: row-major store; else fragment store via LDS transpose.
// ------------------------------------------------------------------
template<int F, int MODE, int ROWOUT>
__global__ __launch_bounds__(256) void k_aggc(
    const _Float16* __restrict__ X, _Float16* __restrict__ Y,
    const int* __restrict__ indptr, const int2* __restrict__ csw,
    const float* __restrict__ rowsum,
    const float* __restrict__ p0, const float* __restrict__ p1,
    const float* __restrict__ p2)
{
  constexpr int NCH = F / 64;
  constexpr int KB  = F / 32;
  __shared__ _Float16 sm[16][72];
  int lin   = blockIdx.x;
  int chunk = lin & (NCH - 1);
  int ng    = lin / NCH;
  int wave  = threadIdx.x >> 6;
  int lane  = threadIdx.x & 63;
  int fbase = chunk * 64;
  int f     = fbase + lane;
  const _Float16* Xc = X + fbase + lane;
  const float inv_n = 1.f / NN;

  float sc = 0.f, sh = 0.f, c0 = 0.f, c1 = 0.f;
  if constexpr (MODE == 0) {
    c0 = p0[f]; c1 = p1[f];
  } else {
    float mean = p0[f] * inv_n;
    float var  = p0[F + f] * inv_n - mean * mean;
    sc = p1[f] * rsqrtf(var + EPS_BN);
    sh = p2[f] - mean * sc;
  }

  #pragma unroll
  for (int ni = 0; ni < 4; ++ni) {
    int node = ng * 16 + wave * 4 + ni;
    int beg = indptr[node], end = indptr[node + 1];
    float a0 = 0.f, a1 = 0.f;
    int e = beg;
    for (; e + 8 <= end; e += 8) {
      #pragma unroll
      for (int u = 0; u < 8; u += 2) {
        int2 m0 = csw[e + u];
        int2 m1 = csw[e + u + 1];
        a0 = fmaf(__builtin_bit_cast(float, m0.y), (float)Xc[(size_t)m0.x * F], a0);
        a1 = fmaf(__builtin_bit_cast(float, m1.y), (float)Xc[(size_t)m1.x * F], a1);
      }
    }
    for (; e < end; ++e) {
      int2 m = csw[e];
      a0 = fmaf(__builtin_bit_cast(float, m.y), (float)Xc[(size_t)m.x * F], a0);
    }
    float acc = a0 + a1;
    float s_n = rowsum[node];
    float v;
    if constexpr (MODE == 0) v = fmaxf(acc + s_n * c0 + c1, 0.f);
    else                     v = sc * acc + s_n * sh;
    if constexpr (ROWOUT) {
      Y[(size_t)node * F + f] = (_Float16)v;
    } else {
      sm[wave * 4 + ni][lane] = (_Float16)v;
    }
  }

  if constexpr (!ROWOUT) {
    __syncthreads();
    int tid = threadIdx.x;
    if (tid < 128) {
      int tile = tid >> 6, n16 = tid & 15, sub = (tid >> 4) & 3;
      _Float16 ov[8];
      #pragma unroll
      for (int i = 0; i < 8; ++i) ov[i] = sm[n16][tile * 32 + sub * 8 + i];
      size_t fa = ((size_t)ng * KB + chunk * 2 + tile) * 512 + sub * 128 + n16 * 8;
      *(uint4*)&Y[fa] = *(const uint4*)ov;
    }
  }
}

// ------------------------------------------------------------------
// Fragment-layout fp16 MFMA GEMM (no K-loop LDS / barriers).
// ------------------------------------------------------------------
template<int K, int FRAGOUT>
__global__ __launch_bounds__(256) void k_gemmf(
    const _Float16* __restrict__ Af, const _Float16* __restrict__ Bf,
    const float* __restrict__ bias,
    _Float16* __restrict__ Ch,          // row-major out (FRAGOUT=0)
    _Float16* __restrict__ Cf,          // fragment out  (FRAGOUT=1)
    float* __restrict__ stats,
    int N, int do_relu, int nbx)
{
  __shared__ __align__(16) _Float16 cs[128 * 136];
  __shared__ float sred[256];

  const int tid  = threadIdx.x;
  const int wave = tid >> 6;
  const int lane = tid & 63;

  int lin = blockIdx.x;
  int xcd = lin & 7, seq = lin >> 3;
  int bx = seq % nbx, grp = seq / nbx;
  int by = xcd + 8 * grp;            // 0..159
  const int row0 = by * 128;
  const int col0 = bx * 128;

  const int q  = lane >> 4;
  const int mm = lane & 15;
  const int wm = wave >> 1;
  const int wn = wave & 1;

  sred[tid] = 0.f;

  constexpr int KB = K / 32;
  const _Float16* pa[4];
  const _Float16* pb[4];
  #pragma unroll
  for (int i = 0; i < 4; ++i)
    pa[i] = Af + (size_t)((row0 >> 4) + wm * 4 + i) * (KB * 512) + lane * 8;
  #pragma unroll
  for (int j = 0; j < 4; ++j)
    pb[j] = Bf + (size_t)((col0 >> 4) + wn * 4 + j) * (KB * 512) + lane * 8;

  floatx4 acc[4][4];
  #pragma unroll
  for (int i = 0; i < 4; ++i)
    #pragma unroll
    for (int j = 0; j < 4; ++j) acc[i][j] = floatx4{0.f, 0.f, 0.f, 0.f};

  half8 av[4], bv[4];
  #pragma unroll
  for (int i = 0; i < 4; ++i) { av[i] = *(const half8*)pa[i]; pa[i] += 512; }
  #pragma unroll
  for (int j = 0; j < 4; ++j) { bv[j] = *(const half8*)pb[j]; pb[j] += 512; }

  #pragma unroll 2
  for (int s = 0; s < KB; ++s) {
    half8 nav[4], nbv[4];
    if (s + 1 < KB) {
      #pragma unroll
      for (int i = 0; i < 4; ++i) { nav[i] = *(const half8*)pa[i]; pa[i] += 512; }
      #pragma unroll
      for (int j = 0; j < 4; ++j) { nbv[j] = *(const half8*)pb[j]; pb[j] += 512; }
    }
    #pragma unroll
    for (int j = 0; j < 4; ++j)
      #pragma unroll
      for (int i = 0; i < 4; ++i)
        acc[i][j] = __builtin_amdgcn_mfma_f32_16x16x32_f16(av[i], bv[j], acc[i][j], 0, 0, 0);
    if (s + 1 < KB) {
      #pragma unroll
      for (int i = 0; i < 4; ++i) av[i] = nav[i];
      #pragma unroll
      for (int j = 0; j < 4; ++j) bv[j] = nbv[j];
    }
  }

  __syncthreads();

  float sloc[4]  = {0.f, 0.f, 0.f, 0.f};
  float s2loc[4] = {0.f, 0.f, 0.f, 0.f};
  #pragma unroll
  for (int j = 0; j < 4; ++j) {
    int cl = wn * 64 + j * 16 + mm;
    float bvv = bias ? bias[col0 + cl] : 0.f;
    #pragma unroll
    for (int i = 0; i < 4; ++i) {
      #pragma unroll
      for (int r = 0; r < 4; ++r) {
        int rl = wm * 64 + i * 16 + q * 4 + r;
        float v = acc[i][j][r] + bvv;
        if (do_relu) v = fmaxf(v, 0.f);
        cs[rl * 136 + cl] = (_Float16)v;
        if (row0 + rl < NN) { sloc[j] += v; s2loc[j] += v * v; }
      }
    }
  }

  if (stats) {
    #pragma unroll
    for (int j = 0; j < 4; ++j) {
      float a = sloc[j], b2 = s2loc[j];
      a  += __shfl_xor(a, 16, 64);  a  += __shfl_xor(a, 32, 64);
      b2 += __shfl_xor(b2, 16, 64); b2 += __shfl_xor(b2, 32, 64);
      if (q == 0) {
        int cl = wn * 64 + j * 16 + mm;
        atomicAdd(&sred[cl], a);
        atomicAdd(&sred[128 + cl], b2);
      }
    }
  }
  __syncthreads();

  if (FRAGOUT) {
    int mlo = tid & 15, sub = (tid >> 4) & 3, kcr = (tid >> 6) & 3;
    int kbN = N >> 5;
    #pragma unroll
    for (int pass = 0; pass < 8; ++pass) {
      int m = pass * 16 + mlo;
      int kl = kcr * 32 + sub * 8;
      uint4 d = *(const uint4*)&cs[m * 136 + kl];
      size_t fa = ((size_t)((row0 >> 4) + pass) * kbN + (col0 >> 5) + kcr) * 512
                + sub * 128 + mlo * 8;
      *(uint4*)&Cf[fa] = d;
    }
  } else {
    #pragma unroll
    for (int pass = 0; pass < 8; ++pass) {
      int cidx = tid + pass * 256;
      int r = cidx >> 4, kc = cidx & 15;
      int rr = row0 + r;
      if (rr < NN) {
        uint4 d = *(const uint4*)&cs[r * 136 + kc * 8];
        *(uint4*)&Ch[(size_t)rr * N + col0 + kc * 8] = d;
      }
    }
  }

  if (stats && tid < 128) {
    atomicAdd(&stats[col0 + tid], sred[tid]);
    atomicAdd(&stats[N + col0 + tid], sred[128 + tid]);
  }
}

// ------------------------------------------------------------------
// BN stats over FRAGMENT-layout fp16 tensor.
// ------------------------------------------------------------------
template<int F>
__global__ __launch_bounds__(256) void k_statsf(const _Float16* __restrict__ Xf,
                                                float* __restrict__ sums) {
  constexpr int KB = F / 32;
  constexpr int NT = NN / 16;
  int wid  = (blockIdx.x * 256 + threadIdx.x) >> 6;
  int lane = threadIdx.x & 63;
  int nw   = (gridDim.x * 256) >> 6;
  int kidx = wid % KB;
  int ng0  = wid / KB;
  int step = nw / KB;
  int sub = lane >> 4, n16 = lane & 15;

  float s[8], s2[8];
  #pragma unroll
  for (int i = 0; i < 8; ++i) { s[i] = 0.f; s2[i] = 0.f; }

  for (int ng = ng0; ng < NT; ng += step) {
    const _Float16* p = Xf + ((size_t)ng * KB + kidx) * 512 + lane * 8;
    uint4 d = *(const uint4*)p;
    unsigned uu[4] = {d.x, d.y, d.z, d.w};
    #pragma unroll
    for (int i = 0; i < 4; ++i) {
      half2v h = __builtin_bit_cast(half2v, uu[i]);
      float v0 = (float)h[0], v1 = (float)h[1];
      s[2 * i]      += v0;  s2[2 * i]     += v0 * v0;
      s[2 * i + 1]  += v1;  s2[2 * i + 1] += v1 * v1;
    }
  }
  #pragma unroll
  for (int o = 1; o < 16; o <<= 1) {
    #pragma unroll
    for (int i = 0; i < 8; ++i) {
      s[i]  += __shfl_xor(s[i],  o, 64);
      s2[i] += __shfl_xor(s2[i], o, 64);
    }
  }
  if (n16 == 0) {
    int f = kidx * 32 + sub * 8;
    #pragma unroll
    for (int i = 0; i < 8; ++i) {
      atomicAdd(&sums[f + i], s[i]);
      atomicAdd(&sums[F + f + i], s2[i]);
    }
  }
}

// ------------------------------------------------------------------
// Slim BN stats over row-major fp16 tensor (stride == F)
// ------------------------------------------------------------------
__global__ __launch_bounds__(256) void k_stats16(const _Float16* __restrict__ X, int F,
                                                 float* __restrict__ sums) {
  int tid = threadIdx.x;
  int npf = F >> 8;
  float s[2] = {0.f, 0.f}, s2[2] = {0.f, 0.f};
  for (int r = blockIdx.x; r < NN; r += gridDim.x) {
    #pragma unroll
    for (int i = 0; i < 2; ++i) {
      if (i < npf) {
        float v = (float)X[(size_t)r * F + tid + i * 256];
        s[i] += v; s2[i] += v * v;
      }
    }
  }
  #pragma unroll
  for (int i = 0; i < 2; ++i) {
    if (i < npf) {
      atomicAdd(&sums[tid + i * 256], s[i]);
      atomicAdd(&sums[F + tid + i * 256], s2[i]);
    }
  }
}

// ------------------------------------------------------------------
// Gate with inline BN5 fold
// ------------------------------------------------------------------
__global__ __launch_bounds__(256) void k_gate2(const _Float16* __restrict__ X,
                                               const float* __restrict__ sums,
                                               const float* __restrict__ g5,
                                               const float* __restrict__ be5,
                                               const float* __restrict__ Wg,
                                               const float* __restrict__ bg,
                                               float* __restrict__ gate) {
  __shared__ float red[512];
  int n = blockIdx.x, tid = threadIdx.x;
  int f = tid * 4;
  const float inv_n = 1.f / NN;
  uint2 u = *(const uint2*)(X + (size_t)n * 1024 + f);
  half2v h0 = __builtin_bit_cast(half2v, u.x);
  half2v h1 = __builtin_bit_cast(half2v, u.y);
  float xv[4] = {(float)h0[0], (float)h0[1], (float)h1[0], (float)h1[1]};
  float s = 0.f, t = 0.f;
  #pragma unroll
  for (int i = 0; i < 4; ++i) {
    int ff = f + i;
    float mean = sums[ff] * inv_n;
    float var  = sums[1024 + ff] * inv_n - mean * mean;
    float sc   = g5[ff] * rsqrtf(var + EPS_BN);
    float sh   = be5[ff] - mean * sc;
    float wg   = Wg[ff];
    s += xv[i] * (sc * wg);
    t += sh * wg;
  }
  red[tid] = s;
  red[256 + tid] = t;
  __syncthreads();
  for (int o = 128; o > 0; o >>= 1) {
    if (tid < o) { red[tid] += red[tid + o]; red[256 + tid] += red[256 + tid + o]; }
    __syncthreads();
  }
  if (tid == 0) gate[n] = red[0] + red[256] + bg[0];
}

// ------------------------------------------------------------------
// Fused segred + pool (BN5 fold, unroll-4 node loop) + MLP head
// ------------------------------------------------------------------
__global__ __launch_bounds__(256) void k_poolhead(
    const _Float16* __restrict__ X, const float* __restrict__ gate,
    const int* __restrict__ goff,
    const float* __restrict__ sums, const float* __restrict__ g5,
    const float* __restrict__ be5,
    const float* __restrict__ Wf2, const float* __restrict__ bf2,
    const float* __restrict__ Wf3, const float* __restrict__ bf3,
    const float* __restrict__ Wf4, const float* __restrict__ bf4,
    float* __restrict__ out)
{
  __shared__ float red[256];
  __shared__ float sp[1024];
  __shared__ float sp2[128];
  __shared__ float sp3[16];
  int g = blockIdx.x, tid = threadIdx.x;
  int beg = goff[g], end = goff[g + 1];
  bool nonempty = end > beg;

  float m = -3.4e38f;
  for (int n = beg + tid; n < end; n += 256) m = fmaxf(m, gate[n]);
  red[tid] = m;
  __syncthreads();
  for (int o = 128; o > 0; o >>= 1) {
    if (tid < o) red[tid] = fmaxf(red[tid], red[tid + o]);
    __syncthreads();
  }
  m = red[0];
  __syncthreads();
  float s = 0.f;
  for (int n = beg + tid; n < end; n += 256) s += expf(gate[n] - m);
  red[tid] = s;
  __syncthreads();
  for (int o = 128; o > 0; o >>= 1) {
    if (tid < o) red[tid] += red[tid + o];
    __syncthreads();
  }
  float inv = nonempty ? (1.f / red[0]) : 0.f;

  int f = tid * 4;
  const float inv_n = 1.f / NN;
  float acc[4] = {0.f, 0.f, 0.f, 0.f};
  if (nonempty) {
    const _Float16* Xf = X + f;
    int n = beg;
    for (; n + 4 <= end; n += 4) {
      float a0 = expf(gate[n]     - m);
      float a1 = expf(gate[n + 1] - m);
      float a2 = expf(gate[n + 2] - m);
      float a3 = expf(gate[n + 3] - m);
      uint2 u0 = *(const uint2*)(Xf + (size_t)(n)     * 1024);
      uint2 u1 = *(const uint2*)(Xf + (size_t)(n + 1) * 1024);
      uint2 u2 = *(const uint2*)(Xf + (size_t)(n + 2) * 1024);
      uint2 u3 = *(const uint2*)(Xf + (size_t)(n + 3) * 1024);
      half2v p00 = __builtin_bit_cast(half2v, u0.x), p01 = __builtin_bit_cast(half2v, u0.y);
      half2v p10 = __builtin_bit_cast(half2v, u1.x), p11 = __builtin_bit_cast(half2v, u1.y);
      half2v p20 = __builtin_bit_cast(half2v, u2.x), p21 = __builtin_bit_cast(half2v, u2.y);
      half2v p30 = __builtin_bit_cast(half2v, u3.x), p31 = __builtin_bit_cast(half2v, u3.y);
      acc[0] += a0 * (float)p00[0] + a1 * (float)p10[0] + a2 * (float)p20[0] + a3 * (float)p30[0];
      acc[1] += a0 * (float)p00[1] + a1 * (float)p10[1] + a2 * (float)p20[1] + a3 * (float)p30[1];
      acc[2] += a0 * (float)p01[0] + a1 * (float)p11[0] + a2 * (float)p21[0] + a3 * (float)p31[0];
      acc[3] += a0 * (float)p01[1] + a1 * (float)p11[1] + a2 * (float)p21[1] + a3 * (float)p31[1];
    }
    for (; n < end; ++n) {
      float a = expf(gate[n] - m);
      uint2 u0 = *(const uint2*)(Xf + (size_t)n * 1024);
      half2v p0 = __builtin_bit_cast(half2v, u0.x), p1 = __builtin_bit_cast(half2v, u0.y);
      acc[0] += a * (float)p0[0];
      acc[1] += a * (float)p0[1];
      acc[2] += a * (float)p1[0];
      acc[3] += a * (float)p1[1];
    }
  }
  #pragma unroll
  for (int i = 0; i < 4; ++i) {
    int ff = f + i;
    float mean = sums[ff] * inv_n;
    float var  = sums[1024 + ff] * inv_n - mean * mean;
    float sc   = g5[ff] * rsqrtf(var + EPS_BN);
    float sh   = be5[ff] - mean * sc;
    sp[ff] = nonempty ? (acc[i] * inv * sc + sh) : 0.f;
  }
  __syncthreads();

  if (tid < 128) {
    float s2 = bf2[tid];
    for (int k = 0; k < 1024; ++k) s2 += sp[k] * Wf2[k * 128 + tid];
    sp2[tid] = fmaxf(s2, 0.f);
  }
  __syncthreads();
  if (tid < 16) {
    float t = bf3[tid];
    for (int k = 0; k < 128; ++k) t += sp2[k] * Wf3[k * 16 + tid];
    sp3[tid] = fmaxf(t, 0.f);
  }
  __syncthreads();
  if (tid == 0) {
    float t = bf4[0];
    for (int k = 0; k < 16; ++k) t += sp3[k] * Wf4[k];
    out[g] = t;
  }
}

// ------------------------------------------------------------------
extern "C" void kernel_launch(void* const* d_in, const int* in_sizes, int n_in,
                              void* d_out, int out_size, void* d_ws, size_t ws_size,
                              hipStream_t stream) {
  const float* x     = (const float*)d_in[0];
  const int*   ei    = (const int*)d_in[1];
  const int*   batch = (const int*)d_in[2];
  const float* W[5]; const float* b[5]; const float* g[5]; const float* be[5];
  for (int l = 0; l < 5; ++l) {
    W[l]  = (const float*)d_in[3 + 4 * l];
    b[l]  = (const float*)d_in[4 + 4 * l];
    g[l]  = (const float*)d_in[5 + 4 * l];
    be[l] = (const float*)d_in[6 + 4 * l];
  }
  const float* Wg  = (const float*)d_in[23];
  const float* bg  = (const float*)d_in[24];
  const float* Wf2 = (const float*)d_in[25];
  const float* bf2 = (const float*)d_in[26];
  const float* Wf3 = (const float*)d_in[27];
  const float* bf3 = (const float*)d_in[28];
  const float* Wf4 = (const float*)d_in[29];
  const float* bf4 = (const float*)d_in[30];
  float* out = (float*)d_out;

  const int* row = ei;
  const int* col = ei + NE;

  char* base = (char*)d_ws;
  size_t off = 0;
  auto alloc = [&](size_t bytes) -> char* {
    char* p = base + off;
    off = (off + bytes + 255) & ~(size_t)255;
    return p;
  };
  // AH: r1(frag,K=1024) -> a4(frag,K=256)
  _Float16*  AH  = (_Float16*)alloc((size_t)MPAD * 1024 * 2);
  // AF: r2(frag,K=512) -> a5(frag,K=512)
  _Float16*  AF  = (_Float16*)alloc((size_t)MPAD * 512 * 2);
  _Float16*  ASM = (_Float16*)alloc((size_t)MPAD * 32 * 2);   // L1 A operand (frag)
  _Float16*  BF  = (_Float16*)alloc((size_t)NN * 512 * 2);    // G2(row) -> r3(row)
  _Float16*  BF2 = (_Float16*)alloc((size_t)NN * 512 * 2);    // G3(row) -> r4(row)
  _Float16*  H5  = (_Float16*)alloc((size_t)NN * 1024 * 2);   // r5(row)
  const int wtsz[5] = {1024 * 32, 512 * 1024, 256 * 512, 512 * 256, 1024 * 512};
  _Float16* WT[5];
  for (int l = 0; l < 5; ++l) WT[l] = (_Float16*)alloc((size_t)wtsz[l] * 2);
  float* c2  = (float*)alloc(512 * 4);
  float* c3  = (float*)alloc(256 * 4);
  float* dinv    = (float*)alloc(NN * 4);
  int*   indptr  = (int*)alloc((NN + 1) * 4);
  int*   cursor  = (int*)alloc(NN * 4);
  int2*  csw     = (int2*)alloc((size_t)NTOT * 8);
  int*   psum    = (int*)alloc((NBLK + 1) * 4);
  int*   pbase   = (int*)alloc((NBLK + 1) * 4);
  int*   goff    = (int*)alloc((NG + 1) * 4);
  float* gate    = (float*)alloc(NN * 4);
  size_t znf = 6656 + NN + NG + NN;
  float* zbase = (float*)alloc(znf * 4);
  float* bns  = zbase;
  int*   deg  = (int*)(zbase + 6656);
  int*   gcnt = (int*)(zbase + 6656 + NN);
  float* rsum = zbase + 6656 + NN + NG;
  float* bns1 = bns;          // F=1024
  float* bns2 = bns + 2048;   // F=512
  float* bns3 = bns + 3072;   // F=256
  float* bns4 = bns + 3584;   // F=512
  float* bns5 = bns + 4608;   // F=1024

  // ---- preprocessing ----
  hipMemsetAsync(zbase, 0, znf * 4, stream);
  k_deg<<<(NTOT + 255) / 256, 256, 0, stream>>>(col, deg, batch, gcnt);
  k_pre1<<<NBLK, 256, 0, stream>>>(deg, dinv, psum);
  k_pre2<<<1, 256, 0, stream>>>(psum, pbase, gcnt, goff);
  k_pre3<<<NBLK, 256, 0, stream>>>(deg, pbase, indptr, cursor);
  k_fill<<<(NTOT + 255) / 256, 256, 0, stream>>>(row, col, dinv, cursor, csw, rsum);
  k_wconv3<<<336, 256, 0, stream>>>(W[0], W[3], W[4], WT[0], WT[3], WT[4]);

  // ---- layer 1 (29 -> 1024): agg-first (frag); GEMM1 frag-out r1 + stats ----
  k_agg29<<<NN, 128, 0, stream>>>(x, indptr, csw, ASM);
  k_gemmf<32, 1><<<8 * 160, 256, 0, stream>>>(ASM, WT[0], b[0], nullptr, AH, bns1, 1024, 1, 8);

  // ---- layer 2 (1024 -> 512): BN1 folded into W2; transform-first ----
  k_wfold<<<512, 256, 0, stream>>>(W[1], 1024, 512, bns1, g[0], be[0], WT[1], c2);
  k_gemmf<1024, 0><<<4 * 160, 256, 0, stream>>>(AH, WT[1], nullptr, BF, nullptr, nullptr, 512, 0, 4); // G2
  k_aggc<512, 0, 0><<<1250 * 8, 256, 0, stream>>>(BF, AF, indptr, csw, rsum, c2, b[1], nullptr); // r2 frag
  k_statsf<512><<<256, 256, 0, stream>>>(AF, bns2);

  // ---- layer 3 (512 -> 256): BN2 folded into W3; transform-first ----
  k_wfold<<<256, 256, 0, stream>>>(W[2], 512, 256, bns2, g[1], be[1], WT[2], c3);
  k_gemmf<512, 0><<<2 * 160, 256, 0, stream>>>(AF, WT[2], nullptr, BF2, nullptr, nullptr, 256, 0, 2); // G3
  k_aggc<256, 0, 1><<<1250 * 4, 256, 0, stream>>>(BF2, BF, indptr, csw, rsum, c3, b[2], nullptr); // r3 row
  k_stats16<<<512, 256, 0, stream>>>(BF, 256, bns3);

  // ---- layer 4 (256 -> 512): agg-first (frag), BN3 inline ----
  k_aggc<256, 1, 0><<<1250 * 4, 256, 0, stream>>>(BF, AH, indptr, csw, rsum, bns3, g[2], be[2]); // a4 frag
  k_gemmf<256, 0><<<4 * 160, 256, 0, stream>>>(AH, WT[3], b[3], BF2, nullptr, bns4, 512, 1, 4); // r4 + stats

  // ---- layer 5 (512 -> 1024): agg-first (frag), BN4 inline ----
  k_aggc<512, 1, 0><<<1250 * 8, 256, 0, stream>>>(BF2, AF, indptr, csw, rsum, bns4, g[3], be[3]); // a5 frag
  k_gemmf<512, 0><<<8 * 160, 256, 0, stream>>>(AF, WT[4], b[4], H5, nullptr, bns5, 1024, 1, 8); // r5 + stats

  // ---- attention pooling (inline BN5 fold) + head ----
  k_gate2<<<NN, 256, 0, stream>>>(H5, bns5, g[4], be[4], Wg, bg, gate);
  k_poolhead<<<NG, 256, 0, stream>>>(H5, gate, goff, bns5, g[4], be[4],
                                     Wf2, bf2, Wf3, bf3, Wf4, bf4, out);
}

// Round 16
// 585.467 us; speedup vs baseline: 1.2112x; 1.2112x over previous
//
#include <hip/hip_runtime.h>

#define EPS_BN 1e-5f

constexpr int NN   = 20000;       // nodes
constexpr int NE   = 320000;      // edges
constexpr int NTOT = NE + NN;     // edges + self loops
constexpr int NG   = 512;        // graphs
constexpr int MPAD = 20480;       // 160 * 128 rows
constexpr int NBLK = 79;          // ceil(NN/256)

typedef _Float16 half8  __attribute__((ext_vector_type(8)));
typedef _Float16 half2v __attribute__((ext_vector_type(2)));
typedef float floatx4   __attribute__((ext_vector_type(4)));

// ------------------------------------------------------------------
// Graph preprocessing
// ------------------------------------------------------------------
__global__ void k_deg(const int* __restrict__ col, int* __restrict__ deg,
                      const int* __restrict__ batch, int* __restrict__ gcnt) {
  int e = blockIdx.x * blockDim.x + threadIdx.x;
  if (e >= NTOT) return;
  int c = (e < NE) ? col[e] : (e - NE);
  atomicAdd(&deg[c], 1);
  if (e < NN) atomicAdd(&gcnt[batch[e]], 1);
}

__global__ __launch_bounds__(256) void k_pre1(const int* __restrict__ deg,
                                              float* __restrict__ dinvv,
                                              int* __restrict__ psum) {
  __shared__ int ws[4];
  int t = threadIdx.x, lane = t & 63, wv = t >> 6;
  int idx = blockIdx.x * 256 + t;
  int d = (idx < NN) ? deg[idx] : 0;
  if (idx < NN) dinvv[idx] = rsqrtf((float)d);
  int s = d;
  for (int o = 1; o < 64; o <<= 1) { int u = __shfl_up(s, o, 64); if (lane >= o) s += u; }
  if (lane == 63) ws[wv] = s;
  __syncthreads();
  if (t == 0) psum[blockIdx.x] = ws[0] + ws[1] + ws[2] + ws[3];
}

__global__ __launch_bounds__(256) void k_pre2(const int* __restrict__ psum,
                                              int* __restrict__ pbase,
                                              const int* __restrict__ gcnt,
                                              int* __restrict__ goff) {
  __shared__ int ws[8];
  int t = threadIdx.x, lane = t & 63, wv = t >> 6;
  int v = (t < NBLK) ? psum[t] : 0;
  int inc = v;
  for (int o = 1; o < 64; o <<= 1) { int u = __shfl_up(inc, o, 64); if (lane >= o) inc += u; }
  if (lane == 63) ws[wv] = inc;
  __syncthreads();
  int base = 0;
  for (int w = 0; w < wv; ++w) base += ws[w];
  int excl = base + inc - v;
  if (t < NBLK) pbase[t] = excl;
  if (t == NBLK - 1) pbase[NBLK] = excl + v;
  __syncthreads();
  int a0 = gcnt[2 * t], a1 = gcnt[2 * t + 1];
  int p = a0 + a1;
  int incp = p;
  for (int o = 1; o < 64; o <<= 1) { int u = __shfl_up(incp, o, 64); if (lane >= o) incp += u; }
  if (lane == 63) ws[4 + wv] = incp;
  __syncthreads();
  int gb = 0;
  for (int w = 0; w < wv; ++w) gb += ws[4 + w];
  int exclp = gb + incp - p;
  goff[2 * t]     = exclp;
  goff[2 * t + 1] = exclp + a0;
  if (t == 255) goff[NG] = exclp + p;
}

__global__ __launch_bounds__(256) void k_pre3(const int* __restrict__ deg,
                                              const int* __restrict__ pbase,
                                              int* __restrict__ indptr,
                                              int* __restrict__ cursor) {
  __shared__ int ws[4];
  int t = threadIdx.x, lane = t & 63, wv = t >> 6;
  int idx = blockIdx.x * 256 + t;
  int d = (idx < NN) ? deg[idx] : 0;
  int inc = d;
  for (int o = 1; o < 64; o <<= 1) { int u = __shfl_up(inc, o, 64); if (lane >= o) inc += u; }
  if (lane == 63) ws[wv] = inc;
  __syncthreads();
  int base = pbase[blockIdx.x];
  for (int w = 0; w < wv; ++w) base += ws[w];
  int excl = base + inc - d;
  if (idx < NN) { indptr[idx] = excl; cursor[idx] = excl; }
  if (idx == NN - 1) indptr[NN] = excl + d;
}

__global__ void k_fill(const int* __restrict__ row, const int* __restrict__ col,
                       const float* __restrict__ dinv, int* __restrict__ cursor,
                       int2* __restrict__ csw, float* __restrict__ rsum) {
  int e = blockIdx.x * blockDim.x + threadIdx.x;
  if (e >= NTOT) return;
  int r, c;
  if (e < NE) { r = row[e]; c = col[e]; } else { r = c = e - NE; }
  float wv = dinv[r] * dinv[c];
  int pos = atomicAdd(&cursor[c], 1);
  int2 m; m.x = r; m.y = __builtin_bit_cast(int, wv);
  csw[pos] = m;
  atomicAdd(&rsum[c], wv);
}

// ------------------------------------------------------------------
// MFMA fragment layout: element (n, k) of an [Nrows, K] operand lives at
// ((n>>4)*(K>>5) + (k>>5))*512 + ((k>>3)&3)*128 + (n&15)*8 + (k&7)
// ------------------------------------------------------------------
__device__ __forceinline__ size_t fragoff(int n, int k, int kb) {
  return ((size_t)(n >> 4) * kb + (k >> 5)) * 512 + ((k >> 3) & 3) * 128 + (n & 15) * 8;
}

__global__ void k_wconv3(const float* __restrict__ W0, const float* __restrict__ W3,
                         const float* __restrict__ W4,
                         _Float16* __restrict__ T0, _Float16* __restrict__ T3,
                         _Float16* __restrict__ T4) {
  int c = blockIdx.x * blockDim.x + threadIdx.x;   // 16B chunk index
  _Float16 ov[8];
  if (c < 4096) {                                  // W1: N=1024, Kp=32 (K=29)
    int n = c >> 2, k = (c & 3) * 8;
    #pragma unroll
    for (int i = 0; i < 8; ++i)
      ov[i] = (_Float16)((k + i < 29) ? W0[(size_t)(k + i) * 1024 + n] : 0.f);
    *(uint4*)&T0[fragoff(n, k, 1)] = *(const uint4*)ov;
  } else if (c < 4096 + 16384) {                   // W4: N=512, K=256
    int c2 = c - 4096;
    int n = c2 >> 5, k = (c2 & 31) * 8;
    #pragma unroll
    for (int i = 0; i < 8; ++i)
      ov[i] = (_Float16)W3[(size_t)(k + i) * 512 + n];
    *(uint4*)&T3[fragoff(n, k, 8)] = *(const uint4*)ov;
  } else if (c < 4096 + 16384 + 65536) {           // W5: N=1024, K=512
    int c3 = c - 20480;
    int n = c3 >> 6, k = (c3 & 63) * 8;
    #pragma unroll
    for (int i = 0; i < 8; ++i)
      ov[i] = (_Float16)W4[(size_t)(k + i) * 1024 + n];
    *(uint4*)&T4[fragoff(n, k, 16)] = *(const uint4*)ov;
  }
}

// W' = diag(sc) W -> fragment layout fp16; c[n] = sum_k sh_k W[k,n]
__global__ __launch_bounds__(256) void k_wfold(const float* __restrict__ W, int K, int N,
                                               const float* __restrict__ sums,
                                               const float* __restrict__ gamma,
                                               const float* __restrict__ beta,
                                               _Float16* __restrict__ T,
                                               float* __restrict__ c) {
  __shared__ float red[256];
  int n = blockIdx.x, tid = threadIdx.x;
  int kb = K >> 5;
  const float inv_n = 1.f / NN;
  float csum = 0.f;
  for (int kc = tid; kc < (K >> 3); kc += 256) {
    int k = kc * 8;
    _Float16 ov[8];
    #pragma unroll
    for (int i = 0; i < 8; ++i) {
      int ki = k + i;
      float mean = sums[ki] * inv_n;
      float var  = sums[K + ki] * inv_n - mean * mean;
      float sc   = gamma[ki] * rsqrtf(var + EPS_BN);
      float sh   = beta[ki] - mean * sc;
      float wv   = W[(size_t)ki * N + n];
      ov[i] = (_Float16)(sc * wv);
      csum += sh * wv;
    }
    *(uint4*)&T[fragoff(n, k, kb)] = *(const uint4*)ov;
  }
  red[tid] = csum;
  __syncthreads();
  for (int o = 128; o > 0; o >>= 1) {
    if (tid < o) red[tid] += red[tid + o];
    __syncthreads();
  }
  if (tid == 0) c[n] = red[0];
}

// ------------------------------------------------------------------
// L1 aggregation: fp32 x (F=29) -> fp16 FRAGMENT out (Kp=32, kb=1)
// ------------------------------------------------------------------
#define AGG_CH 128
__global__ __launch_bounds__(128) void k_agg29(
    const float* __restrict__ X,
    const int* __restrict__ indptr, const int2* __restrict__ csw,
    _Float16* __restrict__ Y) {
  __shared__ int   s_src[AGG_CH];
  __shared__ float s_w[AGG_CH];
  __shared__ float red[128];
  int node = blockIdx.x;
  int tid  = threadIdx.x;
  int sub  = tid / 29;
  int feat = tid - sub * 29;
  bool act = tid < 116;
  int beg = indptr[node], end = indptr[node + 1];
  float acc = 0.f;
  for (int e0 = beg; e0 < end; e0 += AGG_CH) {
    int c = min(AGG_CH, end - e0);
    if (tid < c) {
      int2 m = csw[e0 + tid];
      s_src[tid] = m.x;
      s_w[tid]   = __builtin_bit_cast(float, m.y);
    }
    __syncthreads();
    if (act) {
      for (int j = 0; j < c; j += 4) {
        int jj = j + sub;
        if (jj < c) acc += s_w[jj] * X[(size_t)s_src[jj] * 29 + feat];
      }
    }
    __syncthreads();
  }
  red[tid] = acc;
  __syncthreads();
  if (tid < 32) {
    float v = 0.f;
    if (tid < 29) v = red[tid] + red[29 + tid] + red[58 + tid] + red[87 + tid];
    size_t fb = (size_t)(node >> 4) * 512 + (size_t)(tid >> 3) * 128 + (node & 15) * 8 + (tid & 7);
    Y[fb] = (_Float16)v;
  }
}

// ------------------------------------------------------------------
// Whole-row fp16 gather aggregation F=512, wave-per-node (4 nodes/block).
// Writes fragment-layout Yf (if non-null, kb=16) and/or row-major Yrow.
// MODE 0: out = relu(acc + s*p0[f] + p1[f])
// MODE 1: out = sc[f]*acc + s*sh[f]  (BN from sums p0, gamma p1, beta p2)
// ------------------------------------------------------------------
template<int MODE>
__global__ __launch_bounds__(256) void k_aggv(
    const _Float16* __restrict__ X,
    _Float16* __restrict__ Yf, _Float16* __restrict__ Yrow,
    const int* __restrict__ indptr, const int2* __restrict__ csw,
    const float* __restrict__ rowsum,
    const float* __restrict__ p0, const float* __restrict__ p1,
    const float* __restrict__ p2)
{
  constexpr int F = 512;
  int wave = threadIdx.x >> 6;
  int lane = threadIdx.x & 63;
  int node = blockIdx.x * 4 + wave;
  int beg = indptr[node], end = indptr[node + 1];
  float acc[8];
  #pragma unroll
  for (int i = 0; i < 8; ++i) acc[i] = 0.f;
  const unsigned* Xl = (const unsigned*)X + lane * 4;

  auto body = [&](int e) {
    int2 m = csw[e];
    float we = __builtin_bit_cast(float, m.y);
    uint4 d = *(const uint4*)(Xl + (size_t)m.x * (F / 2));
    unsigned uu[4] = {d.x, d.y, d.z, d.w};
    #pragma unroll
    for (int i = 0; i < 4; ++i) {
      half2v h = __builtin_bit_cast(half2v, uu[i]);
      acc[2 * i]     = fmaf(we, (float)h[0], acc[2 * i]);
      acc[2 * i + 1] = fmaf(we, (float)h[1], acc[2 * i + 1]);
    }
  };
  int e = beg;
  for (; e + 8 <= end; e += 8) {
    body(e); body(e + 1); body(e + 2); body(e + 3);
    body(e + 4); body(e + 5); body(e + 6); body(e + 7);
  }
  for (; e < end; ++e) body(e);

  float s_n = rowsum[node];
  _Float16 outv[8];
  #pragma unroll
  for (int i = 0; i < 8; ++i) {
    int f = lane * 8 + i;
    float v;
    if constexpr (MODE == 0) {
      v = fmaxf(acc[i] + s_n * p0[f] + p1[f], 0.f);
    } else {
      const float inv_n = 1.f / NN;
      float mean = p0[f] * inv_n;
      float var  = p0[F + f] * inv_n - mean * mean;
      float sc   = p1[f] * rsqrtf(var + EPS_BN);
      float sh   = p2[f] - mean * sc;
      v = sc * acc[i] + s_n * sh;
    }
    outv[i] = (_Float16)v;
  }
  if (Yf) {
    size_t fb = (size_t)(node >> 4) * (16 * 512) + lane * 128 + (node & 15) * 8;
    *(uint4*)(Yf + fb) = *(const uint4*)outv;
  }
  if (Yrow) {
    *(uint4*)(Yrow + (size_t)node * F + lane * 8) = *(const uint4*)outv;
  }
}

// ------------------------------------------------------------------
// Paired-node fp16 gather aggregation F=256 (2 nodes/wave, 16B loads).
// ------------------------------------------------------------------
template<int MODE>
__global__ __launch_bounds__(256) void k_aggp(
    const _Float16* __restrict__ X,
    _Float16* __restrict__ Yf, _Float16* __restrict__ Yrow,
    const int* __restrict__ indptr, const int2* __restrict__ csw,
    const float* __restrict__ rowsum,
    const float* __restrict__ p0, const float* __restrict__ p1,
    const float* __restrict__ p2)
{
  constexpr int F = 256;
  int wave = threadIdx.x >> 6;
  int lane = threadIdx.x & 63;
  int half = lane >> 5;
  int l32  = lane & 31;
  int node = blockIdx.x * 8 + wave * 2 + half;
  int beg = indptr[node], end = indptr[node + 1];
  int len = end - beg;
  int len0 = __shfl(len, 0, 64);
  int len1 = __shfl(len, 32, 64);
  int maxlen = max(len0, len1);

  float acc[8];
  #pragma unroll
  for (int i = 0; i < 8; ++i) acc[i] = 0.f;
  const unsigned* Xl = (const unsigned*)X + l32 * 4;

  auto body = [&](int t) {
    int e = beg + min(t, len - 1);
    int2 m = csw[e];
    float we = (t < len) ? __builtin_bit_cast(float, m.y) : 0.f;
    uint4 d = *(const uint4*)(Xl + (size_t)m.x * (F / 2));
    unsigned uu[4] = {d.x, d.y, d.z, d.w};
    #pragma unroll
    for (int i = 0; i < 4; ++i) {
      half2v h = __builtin_bit_cast(half2v, uu[i]);
      acc[2 * i]     = fmaf(we, (float)h[0], acc[2 * i]);
      acc[2 * i + 1] = fmaf(we, (float)h[1], acc[2 * i + 1]);
    }
  };
  int t = 0;
  for (; t + 4 <= maxlen; t += 4) { body(t); body(t + 1); body(t + 2); body(t + 3); }
  for (; t < maxlen; ++t) body(t);

  float s_n = rowsum[node];
  _Float16 outv[8];
  #pragma unroll
  for (int i = 0; i < 8; ++i) {
    int f = l32 * 8 + i;
    float v;
    if constexpr (MODE == 0) {
      v = fmaxf(acc[i] + s_n * p0[f] + p1[f], 0.f);
    } else {
      const float inv_n = 1.f / NN;
      float mean = p0[f] * inv_n;
      float var  = p0[F + f] * inv_n - mean * mean;
      float sc   = p1[f] * rsqrtf(var + EPS_BN);
      float sh   = p2[f] - mean * sc;
      v = sc * acc[i] + s_n * sh;
    }
    outv[i] = (_Float16)v;
  }
  if (Yf) {
    size_t fb = (size_t)(node >> 4) * (8 * 512) + l32 * 128 + (node & 15) * 8;
    *(uint4*)(Yf + fb) = *(const uint4*)outv;
  }
  if (Yrow) {
    *(uint4*)(Yrow + (size_t)node * F + l32 * 8) = *(const uint4*)outv;
  }
}

// ------------------------------------------------------------------
// Fragment-layout fp16 MFMA GEMM (no K-loop LDS / barriers).
// ------------------------------------------------------------------
template<int K, int FRAGOUT>
__global__ __launch_bounds__(256) void k_gemmf(
    const _Float16* __restrict__ Af, const _Float16* __restrict__ Bf,
    const float* __restrict__ bias,
    _Float16* __restrict__ Ch,          // row-major out (FRAGOUT=0)
    _Float16* __restrict__ Cf,          // fragment out  (FRAGOUT=1)
    float* __restrict__ stats,
    int N, int do_relu, int nbx)
{
  __shared__ __align__(16) _Float16 cs[128 * 136];
  __shared__ float sred[256];

  const int tid  = threadIdx.x;
  const int wave = tid >> 6;
  const int lane = tid & 63;

  int lin = blockIdx.x;
  int xcd = lin & 7, seq = lin >> 3;
  int bx = seq % nbx, grp = seq / nbx;
  int by = xcd + 8 * grp;            // 0..159
  const int row0 = by * 128;
  const int col0 = bx * 128;

  const int q  = lane >> 4;
  const int mm = lane & 15;
  const int wm = wave >> 1;
  const int wn = wave & 1;

  sred[tid] = 0.f;

  constexpr int KB = K / 32;
  const _Float16* pa[4];
  const _Float16* pb[4];
  #pragma unroll
  for (int i = 0; i < 4; ++i)
    pa[i] = Af + (size_t)((row0 >> 4) + wm * 4 + i) * (KB * 512) + lane * 8;
  #pragma unroll
  for (int j = 0; j < 4; ++j)
    pb[j] = Bf + (size_t)((col0 >> 4) + wn * 4 + j) * (KB * 512) + lane * 8;

  floatx4 acc[4][4];
  #pragma unroll
  for (int i = 0; i < 4; ++i)
    #pragma unroll
    for (int j = 0; j < 4; ++j) acc[i][j] = floatx4{0.f, 0.f, 0.f, 0.f};

  half8 av[4], bv[4];
  #pragma unroll
  for (int i = 0; i < 4; ++i) { av[i] = *(const half8*)pa[i]; pa[i] += 512; }
  #pragma unroll
  for (int j = 0; j < 4; ++j) { bv[j] = *(const half8*)pb[j]; pb[j] += 512; }

  #pragma unroll 2
  for (int s = 0; s < KB; ++s) {
    half8 nav[4], nbv[4];
    if (s + 1 < KB) {
      #pragma unroll
      for (int i = 0; i < 4; ++i) { nav[i] = *(const half8*)pa[i]; pa[i] += 512; }
      #pragma unroll
      for (int j = 0; j < 4; ++j) { nbv[j] = *(const half8*)pb[j]; pb[j] += 512; }
    }
    #pragma unroll
    for (int j = 0; j < 4; ++j)
      #pragma unroll
      for (int i = 0; i < 4; ++i)
        acc[i][j] = __builtin_amdgcn_mfma_f32_16x16x32_f16(av[i], bv[j], acc[i][j], 0, 0, 0);
    if (s + 1 < KB) {
      #pragma unroll
      for (int i = 0; i < 4; ++i) av[i] = nav[i];
      #pragma unroll
      for (int j = 0; j < 4; ++j) bv[j] = nbv[j];
    }
  }

  __syncthreads();

  float sloc[4]  = {0.f, 0.f, 0.f, 0.f};
  float s2loc[4] = {0.f, 0.f, 0.f, 0.f};
  #pragma unroll
  for (int j = 0; j < 4; ++j) {
    int cl = wn * 64 + j * 16 + mm;
    float bvv = bias ? bias[col0 + cl] : 0.f;
    #pragma unroll
    for (int i = 0; i < 4; ++i) {
      #pragma unroll
      for (int r = 0; r < 4; ++r) {
        int rl = wm * 64 + i * 16 + q * 4 + r;
        float v = acc[i][j][r] + bvv;
        if (do_relu) v = fmaxf(v, 0.f);
        cs[rl * 136 + cl] = (_Float16)v;
        if (row0 + rl < NN) { sloc[j] += v; s2loc[j] += v * v; }
      }
    }
  }

  if (stats) {
    #pragma unroll
    for (int j = 0; j < 4; ++j) {
      float a = sloc[j], b2 = s2loc[j];
      a  += __shfl_xor(a, 16, 64);  a  += __shfl_xor(a, 32, 64);
      b2 += __shfl_xor(b2, 16, 64); b2 += __shfl_xor(b2, 32, 64);
      if (q == 0) {
        int cl = wn * 64 + j * 16 + mm;
        atomicAdd(&sred[cl], a);
        atomicAdd(&sred[128 + cl], b2);
      }
    }
  }
  __syncthreads();

  if (FRAGOUT) {
    int mlo = tid & 15, sub = (tid >> 4) & 3, kcr = (tid >> 6) & 3;
    int kbN = N >> 5;
    #pragma unroll
    for (int pass = 0; pass < 8; ++pass) {
      int m = pass * 16 + mlo;
      int kl = kcr * 32 + sub * 8;
      uint4 d = *(const uint4*)&cs[m * 136 + kl];
      size_t fa = ((size_t)((row0 >> 4) + pass) * kbN + (col0 >> 5) + kcr) * 512
                + sub * 128 + mlo * 8;
      *(uint4*)&Cf[fa] = d;
    }
  } else {
    #pragma unroll
    for (int pass = 0; pass < 8; ++pass) {
      int cidx = tid + pass * 256;
      int r = cidx >> 4, kc = cidx & 15;
      int rr = row0 + r;
      if (rr < NN) {
        uint4 d = *(const uint4*)&cs[r * 136 + kc * 8];
        *(uint4*)&Ch[(size_t)rr * N + col0 + kc * 8] = d;
      }
    }
  }

  if (stats && tid < 128) {
    atomicAdd(&stats[col0 + tid], sred[tid]);
    atomicAdd(&stats[N + col0 + tid], sred[128 + tid]);
  }
}

// ------------------------------------------------------------------
// BN stats over FRAGMENT-layout fp16 tensor.
// ------------------------------------------------------------------
template<int F>
__global__ __launch_bounds__(256) void k_statsf(const _Float16* __restrict__ Xf,
                                                float* __restrict__ sums) {
  constexpr int KB = F / 32;
  constexpr int NT = NN / 16;
  int wid  = (blockIdx.x * 256 + threadIdx.x) >> 6;
  int lane = threadIdx.x & 63;
  int nw   = (gridDim.x * 256) >> 6;
  int kidx = wid % KB;
  int ng0  = wid / KB;
  int step = nw / KB;
  int sub = lane >> 4, n16 = lane & 15;

  float s[8], s2[8];
  #pragma unroll
  for (int i = 0; i < 8; ++i) { s[i] = 0.f; s2[i] = 0.f; }

  for (int ng = ng0; ng < NT; ng += step) {
    const _Float16* p = Xf + ((size_t)ng * KB + kidx) * 512 + lane * 8;
    uint4 d = *(const uint4*)p;
    unsigned uu[4] = {d.x, d.y, d.z, d.w};
    #pragma unroll
    for (int i = 0; i < 4; ++i) {
      half2v h = __builtin_bit_cast(half2v, uu[i]);
      float v0 = (float)h[0], v1 = (float)h[1];
      s[2 * i]      += v0;  s2[2 * i]     += v0 * v0;
      s[2 * i + 1]  += v1;  s2[2 * i + 1] += v1 * v1;
    }
  }
  #pragma unroll
  for (int o = 1; o < 16; o <<= 1) {
    #pragma unroll
    for (int i = 0; i < 8; ++i) {
      s[i]  += __shfl_xor(s[i],  o, 64);
      s2[i] += __shfl_xor(s2[i], o, 64);
    }
  }
  if (n16 == 0) {
    int f = kidx * 32 + sub * 8;
    #pragma unroll
    for (int i = 0; i < 8; ++i) {
      atomicAdd(&sums[f + i], s[i]);
      atomicAdd(&sums[F + f + i], s2[i]);
    }
  }
}

// ------------------------------------------------------------------
// Slim BN stats over row-major fp16 tensor (stride == F)
// ------------------------------------------------------------------
__global__ __launch_bounds__(256) void k_stats16(const _Float16* __restrict__ X, int F,
                                                 float* __restrict__ sums) {
  int tid = threadIdx.x;
  int npf = F >> 8;
  float s[2] = {0.f, 0.f}, s2[2] = {0.f, 0.f};
  for (int r = blockIdx.x; r < NN; r += gridDim.x) {
    #pragma unroll
    for (int i = 0; i < 2; ++i) {
      if (i < npf) {
        float v = (float)X[(size_t)r * F + tid + i * 256];
        s[i] += v; s2[i] += v * v;
      }
    }
  }
  #pragma unroll
  for (int i = 0; i < 2; ++i) {
    if (i < npf) {
      atomicAdd(&sums[tid + i * 256], s[i]);
      atomicAdd(&sums[F + tid + i * 256], s2[i]);
    }
  }
}

// ------------------------------------------------------------------
// Gate with inline BN5 fold
// ------------------------------------------------------------------
__global__ __launch_bounds__(256) void k_gate2(const _Float16* __restrict__ X,
                                               const float* __restrict__ sums,
                                               const float* __restrict__ g5,
                                               const float* __restrict__ be5,
                                               const float* __restrict__ Wg,
                                               const float* __restrict__ bg,
                                               float* __restrict__ gate) {
  __shared__ float red[512];
  int n = blockIdx.x, tid = threadIdx.x;
  int f = tid * 4;
  const float inv_n = 1.f / NN;
  uint2 u = *(const uint2*)(X + (size_t)n * 1024 + f);
  half2v h0 = __builtin_bit_cast(half2v, u.x);
  half2v h1 = __builtin_bit_cast(half2v, u.y);
  float xv[4] = {(float)h0[0], (float)h0[1], (float)h1[0], (float)h1[1]};
  float s = 0.f, t = 0.f;
  #pragma unroll
  for (int i = 0; i < 4; ++i) {
    int ff = f + i;
    float mean = sums[ff] * inv_n;
    float var  = sums[1024 + ff] * inv_n - mean * mean;
    float sc   = g5[ff] * rsqrtf(var + EPS_BN);
    float sh   = be5[ff] - mean * sc;
    float wg   = Wg[ff];
    s += xv[i] * (sc * wg);
    t += sh * wg;
  }
  red[tid] = s;
  red[256 + tid] = t;
  __syncthreads();
  for (int o = 128; o > 0; o >>= 1) {
    if (tid < o) { red[tid] += red[tid + o]; red[256 + tid] += red[256 + tid + o]; }
    __syncthreads();
  }
  if (tid == 0) gate[n] = red[0] + red[256] + bg[0];
}

// ------------------------------------------------------------------
// Fused segred + pool (BN5 fold, unroll-4 node loop) + MLP head
// ------------------------------------------------------------------
__global__ __launch_bounds__(256) void k_poolhead(
    const _Float16* __restrict__ X, const float* __restrict__ gate,
    const int* __restrict__ goff,
    const float* __restrict__ sums, const float* __restrict__ g5,
    const float* __restrict__ be5,
    const float* __restrict__ Wf2, const float* __restrict__ bf2,
    const float* __restrict__ Wf3, const float* __restrict__ bf3,
    const float* __restrict__ Wf4, const float* __restrict__ bf4,
    float* __restrict__ out)
{
  __shared__ float red[256];
  __shared__ float sp[1024];
  __shared__ float sp2[128];
  __shared__ float sp3[16];
  int g = blockIdx.x, tid = threadIdx.x;
  int beg = goff[g], end = goff[g + 1];
  bool nonempty = end > beg;

  float m = -3.4e38f;
  for (int n = beg + tid; n < end; n += 256) m = fmaxf(m, gate[n]);
  red[tid] = m;
  __syncthreads();
  for (int o = 128; o > 0; o >>= 1) {
    if (tid < o) red[tid] = fmaxf(red[tid], red[tid + o]);
    __syncthreads();
  }
  m = red[0];
  __syncthreads();
  float s = 0.f;
  for (int n = beg + tid; n < end; n += 256) s += expf(gate[n] - m);
  red[tid] = s;
  __syncthreads();
  for (int o = 128; o > 0; o >>= 1) {
    if (tid < o) red[tid] += red[tid + o];
    __syncthreads();
  }
  float inv = nonempty ? (1.f / red[0]) : 0.f;

  int f = tid * 4;
  const float inv_n = 1.f / NN;
  float acc[4] = {0.f, 0.f, 0.f, 0.f};
  if (nonempty) {
    const _Float16* Xf = X + f;
    int n = beg;
    for (; n + 4 <= end; n += 4) {
      float a0 = expf(gate[n]     - m);
      float a1 = expf(gate[n + 1] - m);
      float a2 = expf(gate[n + 2] - m);
      float a3 = expf(gate[n + 3] - m);
      uint2 u0 = *(const uint2*)(Xf + (size_t)(n)     * 1024);
      uint2 u1 = *(const uint2*)(Xf + (size_t)(n + 1) * 1024);
      uint2 u2 = *(const uint2*)(Xf + (size_t)(n + 2) * 1024);
      uint2 u3 = *(const uint2*)(Xf + (size_t)(n + 3) * 1024);
      half2v p00 = __builtin_bit_cast(half2v, u0.x), p01 = __builtin_bit_cast(half2v, u0.y);
      half2v p10 = __builtin_bit_cast(half2v, u1.x), p11 = __builtin_bit_cast(half2v, u1.y);
      half2v p20 = __builtin_bit_cast(half2v, u2.x), p21 = __builtin_bit_cast(half2v, u2.y);
      half2v p30 = __builtin_bit_cast(half2v, u3.x), p31 = __builtin_bit_cast(half2v, u3.y);
      acc[0] += a0 * (float)p00[0] + a1 * (float)p10[0] + a2 * (float)p20[0] + a3 * (float)p30[0];
      acc[1] += a0 * (float)p00[1] + a1 * (float)p10[1] + a2 * (float)p20[1] + a3 * (float)p30[1];
      acc[2] += a0 * (float)p01[0] + a1 * (float)p11[0] + a2 * (float)p21[0] + a3 * (float)p31[0];
      acc[3] += a0 * (float)p01[1] + a1 * (float)p11[1] + a2 * (float)p21[1] + a3 * (float)p31[1];
    }
    for (; n < end; ++n) {
      float a = expf(gate[n] - m);
      uint2 u0 = *(const uint2*)(Xf + (size_t)n * 1024);
      half2v p0 = __builtin_bit_cast(half2v, u0.x), p1 = __builtin_bit_cast(half2v, u0.y);
      acc[0] += a * (float)p0[0];
      acc[1] += a * (float)p0[1];
      acc[2] += a * (float)p1[0];
      acc[3] += a * (float)p1[1];
    }
  }
  #pragma unroll
  for (int i = 0; i < 4; ++i) {
    int ff = f + i;
    float mean = sums[ff] * inv_n;
    float var  = sums[1024 + ff] * inv_n - mean * mean;
    float sc   = g5[ff] * rsqrtf(var + EPS_BN);
    float sh   = be5[ff] - mean * sc;
    sp[ff] = nonempty ? (acc[i] * inv * sc + sh) : 0.f;
  }
  __syncthreads();

  if (tid < 128) {
    float s2 = bf2[tid];
    for (int k = 0; k < 1024; ++k) s2 += sp[k] * Wf2[k * 128 + tid];
    sp2[tid] = fmaxf(s2, 0.f);
  }
  __syncthreads();
  if (tid < 16) {
    float t = bf3[tid];
    for (int k = 0; k < 128; ++k) t += sp2[k] * Wf3[k * 16 + tid];
    sp3[tid] = fmaxf(t, 0.f);
  }
  __syncthreads();
  if (tid == 0) {
    float t = bf4[0];
    for (int k = 0; k < 16; ++k) t += sp3[k] * Wf4[k];
    out[g] = t;
  }
}

// ------------------------------------------------------------------
extern "C" void kernel_launch(void* const* d_in, const int* in_sizes, int n_in,
                              void* d_out, int out_size, void* d_ws, size_t ws_size,
                              hipStream_t stream) {
  const float* x     = (const float*)d_in[0];
  const int*   ei    = (const int*)d_in[1];
  const int*   batch = (const int*)d_in[2];
  const float* W[5]; const float* b[5]; const float* g[5]; const float* be[5];
  for (int l = 0; l < 5; ++l) {
    W[l]  = (const float*)d_in[3 + 4 * l];
    b[l]  = (const float*)d_in[4 + 4 * l];
    g[l]  = (const float*)d_in[5 + 4 * l];
    be[l] = (const float*)d_in[6 + 4 * l];
  }
  const float* Wg  = (const float*)d_in[23];
  const float* bg  = (const float*)d_in[24];
  const float* Wf2 = (const float*)d_in[25];
  const float* bf2 = (const float*)d_in[26];
  const float* Wf3 = (const float*)d_in[27];
  const float* bf3 = (const float*)d_in[28];
  const float* Wf4 = (const float*)d_in[29];
  const float* bf4 = (const float*)d_in[30];
  float* out = (float*)d_out;

  const int* row = ei;
  const int* col = ei + NE;

  char* base = (char*)d_ws;
  size_t off = 0;
  auto alloc = [&](size_t bytes) -> char* {
    char* p = base + off;
    off = (off + bytes + 255) & ~(size_t)255;
    return p;
  };
  // AH: r1(frag,K=1024) -> a4(frag,K=256)
  _Float16*  AH  = (_Float16*)alloc((size_t)MPAD * 1024 * 2);
  // AF: r2(frag,K=512) -> a5(frag,K=512)
  _Float16*  AF  = (_Float16*)alloc((size_t)MPAD * 512 * 2);
  _Float16*  ASM = (_Float16*)alloc((size_t)MPAD * 32 * 2);   // L1 A operand (frag)
  _Float16*  BF  = (_Float16*)alloc((size_t)NN * 512 * 2);    // G2(row) -> r3(row)
  _Float16*  BF2 = (_Float16*)alloc((size_t)NN * 512 * 2);    // G3(row) -> r4(row)
  _Float16*  H5  = (_Float16*)alloc((size_t)NN * 1024 * 2);   // r5(row)
  const int wtsz[5] = {1024 * 32, 512 * 1024, 256 * 512, 512 * 256, 1024 * 512};
  _Float16* WT[5];
  for (int l = 0; l < 5; ++l) WT[l] = (_Float16*)alloc((size_t)wtsz[l] * 2);
  float* c2  = (float*)alloc(512 * 4);
  float* c3  = (float*)alloc(256 * 4);
  float* dinv    = (float*)alloc(NN * 4);
  int*   indptr  = (int*)alloc((NN + 1) * 4);
  int*   cursor  = (int*)alloc(NN * 4);
  int2*  csw     = (int2*)alloc((size_t)NTOT * 8);
  int*   psum    = (int*)alloc((NBLK + 1) * 4);
  int*   pbase   = (int*)alloc((NBLK + 1) * 4);
  int*   goff    = (int*)alloc((NG + 1) * 4);
  float* gate    = (float*)alloc(NN * 4);
  size_t znf = 6656 + NN + NG + NN;
  float* zbase = (float*)alloc(znf * 4);
  float* bns  = zbase;
  int*   deg  = (int*)(zbase + 6656);
  int*   gcnt = (int*)(zbase + 6656 + NN);
  float* rsum = zbase + 6656 + NN + NG;
  float* bns1 = bns;          // F=1024
  float* bns2 = bns + 2048;   // F=512
  float* bns3 = bns + 3072;   // F=256
  float* bns4 = bns + 3584;   // F=512
  float* bns5 = bns + 4608;   // F=1024

  // ---- preprocessing ----
  hipMemsetAsync(zbase, 0, znf * 4, stream);
  k_deg<<<(NTOT + 255) / 256, 256, 0, stream>>>(col, deg, batch, gcnt);
  k_pre1<<<NBLK, 256, 0, stream>>>(deg, dinv, psum);
  k_pre2<<<1, 256, 0, stream>>>(psum, pbase, gcnt, goff);
  k_pre3<<<NBLK, 256, 0, stream>>>(deg, pbase, indptr, cursor);
  k_fill<<<(NTOT + 255) / 256, 256, 0, stream>>>(row, col, dinv, cursor, csw, rsum);
  k_wconv3<<<336, 256, 0, stream>>>(W[0], W[3], W[4], WT[0], WT[3], WT[4]);

  // ---- layer 1 (29 -> 1024): agg-first (frag); GEMM1 frag-out r1 + stats ----
  k_agg29<<<NN, 128, 0, stream>>>(x, indptr, csw, ASM);
  k_gemmf<32, 1><<<8 * 160, 256, 0, stream>>>(ASM, WT[0], b[0], nullptr, AH, bns1, 1024, 1, 8);

  // ---- layer 2 (1024 -> 512): BN1 folded into W2; transform-first ----
  k_wfold<<<512, 256, 0, stream>>>(W[1], 1024, 512, bns1, g[0], be[0], WT[1], c2);
  k_gemmf<1024, 0><<<4 * 160, 256, 0, stream>>>(AH, WT[1], nullptr, BF, nullptr, nullptr, 512, 0, 4); // G2
  k_aggv<0><<<NN / 4, 256, 0, stream>>>(BF, AF, nullptr, indptr, csw, rsum, c2, b[1], nullptr); // r2 frag
  k_statsf<512><<<256, 256, 0, stream>>>(AF, bns2);

  // ---- layer 3 (512 -> 256): BN2 folded into W3; transform-first ----
  k_wfold<<<256, 256, 0, stream>>>(W[2], 512, 256, bns2, g[1], be[1], WT[2], c3);
  k_gemmf<512, 0><<<2 * 160, 256, 0, stream>>>(AF, WT[2], nullptr, BF2, nullptr, nullptr, 256, 0, 2); // G3
  k_aggp<0><<<NN / 8, 256, 0, stream>>>(BF2, nullptr, BF, indptr, csw, rsum, c3, b[2], nullptr); // r3 row
  k_stats16<<<512, 256, 0, stream>>>(BF, 256, bns3);

  // ---- layer 4 (256 -> 512): agg-first (frag), BN3 inline ----
  k_aggp<1><<<NN / 8, 256, 0, stream>>>(BF, AH, nullptr, indptr, csw, rsum, bns3, g[2], be[2]); // a4 frag
  k_gemmf<256, 0><<<4 * 160, 256, 0, stream>>>(AH, WT[3], b[3], BF2, nullptr, bns4, 512, 1, 4); // r4 + stats

  // ---- layer 5 (512 -> 1024): agg-first (frag), BN4 inline ----
  k_aggv<1><<<NN / 4, 256, 0, stream>>>(BF2, AF, nullptr, indptr, csw, rsum, bns4, g[3], be[3]); // a5 frag
  k_gemmf<512, 0><<<8 * 160, 256, 0, stream>>>(AF, WT[4], b[4], H5, nullptr, bns5, 1024, 1, 8); // r5 + stats

  // ---- attention pooling (inline BN5 fold) + head ----
  k_gate2<<<NN, 256, 0, stream>>>(H5, bns5, g[4], be[4], Wg, bg, gate);
  k_poolhead<<<NG, 256, 0, stream>>>(H5, gate, goff, bns5, g[4], be[4],
                                     Wf2, bf2, Wf3, bf3, Wf4, bf4, out);
}